// Round 1
// 589.397 us; speedup vs baseline: 1.6106x; 1.6106x over previous
//
#include <hip/hip_runtime.h>

// Problem constants (fixed by setup_inputs)
#define BB 8
#define DD 32
#define HH 512
#define WW 512
#define HWSZ (HH*WW)          // 262144 = 2^18
#define NPIX (BB*HWSZ)        // 2097152
#define CC 19
#define EPSF 1e-8f

// Global accumulator layout: per class 65 floats:
// [0..31]=sum(x), [32..63]=sum(x/|x|), [64]=count
#define CSTRIDE 65
#define ACCSZ (CC*CSTRIDE)    // 1235 floats

// ---- k1 tiling ----
#define P 256                 // pixels per tile (divides HWSZ)
#define XSTR 264              // LDS x-row stride in floats; 264%32==8 -> bank-rotated rows
#define NT1 256
#define NB1 1024              // 4 blocks/CU * 256 CUs
#define NTILES (NPIX/P)       // 8192
#define TPB (HWSZ/P)          // 1024 tiles per batch image

// LDS layout (float offsets):
//   [0, 32*XSTR)      x tile            (33792 B)
//   LX_INVN..+256     invn per pixel    (1024 B)
//   LX_LABS..+256     labels (int)      (1024 B)
//   LX_SS..+1024      partial sq-sums   (4096 B)  sspart[4][64] float4
#define LX_INVN (32*XSTR)         // 8448
#define LX_LABS (LX_INVN + P)     // 8704
#define LX_SS   (LX_LABS + P)     // 8960
#define LTOT    (LX_SS + 1024)    // 9984 floats = 39936 B -> 4 blocks/CU

__global__ void k0_zero(float* __restrict__ acc)
{
    int i = blockIdx.x * 256 + threadIdx.x;
    if (i < ACCSZ) acc[i] = 0.f;
}

// ---- tiny label histogram (counts) -> acc[c*65+64] ----
#define NCB 256
__global__ __launch_bounds__(256) void k_count(const int* __restrict__ tgt,
                                               float* __restrict__ acc)
{
    __shared__ float h[32*20];   // 32 copies x 19 classes (stride 20)
    const int t = threadIdx.x;
    for (int i = t; i < 32*20; i += 256) h[i] = 0.f;
    __syncthreads();
    float* my = h + (t & 31) * 20;
    const int T = NCB * 256;                 // 65536 threads
    int tid = blockIdx.x * 256 + t;
    for (int i = tid; i < NPIX/4; i += T) {
        int4 lv = ((const int4*)tgt)[i];
        unsafeAtomicAdd(my + lv.x, 1.f);
        unsafeAtomicAdd(my + lv.y, 1.f);
        unsafeAtomicAdd(my + lv.z, 1.f);
        unsafeAtomicAdd(my + lv.w, 1.f);
    }
    __syncthreads();
    if (t < CC) {
        float s = 0.f;
        #pragma unroll
        for (int k = 0; k < 32; k++) s += h[k*20 + t];
        unsafeAtomicAdd(acc + t*CSTRIDE + 64, s);
    }
}

// per-element class-select accumulate: 1 cmp + 1 cndmask + 2 fma per class
#define PROC(XX, NN, LL)                                  \
    {                                                     \
        const float x_  = (XX);                           \
        const float xn_ = x_ * (NN);                      \
        const int   l_  = (LL);                           \
        _Pragma("unroll")                                 \
        for (int c = 0; c < CC; c++) {                    \
            const float m_ = (l_ == c) ? 1.0f : 0.0f;     \
            aS[c] = fmaf(m_, x_,  aS[c]);                 \
            aN[c] = fmaf(m_, xn_, aN[c]);                 \
        }                                                 \
    }

__global__ __launch_bounds__(NT1, 4) void k1_accum(
    const float* __restrict__ in, const int* __restrict__ tgt,
    float* __restrict__ acc)
{
    __shared__ __align__(16) float sm[LTOT];
    const int t = threadIdx.x;

    float aS[CC], aN[CC];
    #pragma unroll
    for (int c = 0; c < CC; c++) { aS[c] = 0.f; aN[c] = 0.f; }

    const int dq  = t >> 6;        // 0..3 : group of 8 d-rows (staging)
    const int q   = t & 63;        // quad-column (staging)
    const int d   = t >> 3;        // 0..31 : owned dim (phase 2)
    const int sub = t & 7;         // pixel sub-slice (phase 2)
    const float* xrow = sm + d * XSTR;

    for (int tl = blockIdx.x; tl < NTILES; tl += gridDim.x) {
        const int b  = tl / TPB;                 // TPB = 1024 (pow2: cheap)
        const int hw = (tl & (TPB - 1)) * P;
        const float* gb = in + ((size_t)(b*DD + dq*8) * HWSZ) + hw + 4*q;

        // --- stage labels (wave 0) ---
        if (t < 64) {
            int4 lv = *(const int4*)(tgt + (size_t)tl * P + 4*t);
            *(int4*)((int*)sm + LX_LABS + 4*t) = lv;
        }

        // --- stage x tile: each thread 8 rows x 1 float4 column; partial sq-sums ---
        float4 ss = make_float4(0.f, 0.f, 0.f, 0.f);
        #pragma unroll
        for (int dd = 0; dd < 8; dd++) {
            float4 x = *(const float4*)(gb + (size_t)dd * HWSZ);
            ss.x = fmaf(x.x, x.x, ss.x);
            ss.y = fmaf(x.y, x.y, ss.y);
            ss.z = fmaf(x.z, x.z, ss.z);
            ss.w = fmaf(x.w, x.w, ss.w);
            *(float4*)(sm + (dq*8 + dd)*XSTR + 4*q) = x;
        }
        *(float4*)(sm + LX_SS + (dq*64 + q)*4) = ss;
        __syncthreads();

        // --- finalize per-pixel inverse norms (wave 0) ---
        if (t < 64) {
            float4 s0 = *(const float4*)(sm + LX_SS +        4*t);
            float4 s1 = *(const float4*)(sm + LX_SS + 256  + 4*t);
            float4 s2 = *(const float4*)(sm + LX_SS + 512  + 4*t);
            float4 s3 = *(const float4*)(sm + LX_SS + 768  + 4*t);
            float4 iv;
            iv.x = rsqrtf(fmaxf(s0.x + s1.x + s2.x + s3.x, 1e-30f));
            iv.y = rsqrtf(fmaxf(s0.y + s1.y + s2.y + s3.y, 1e-30f));
            iv.z = rsqrtf(fmaxf(s0.z + s1.z + s2.z + s3.z, 1e-30f));
            iv.w = rsqrtf(fmaxf(s0.w + s1.w + s2.w + s3.w, 1e-30f));
            *(float4*)(sm + LX_INVN + 4*t) = iv;
        }
        __syncthreads();

        // --- phase 2: per-(d,sub) register accumulation, 19-way select ---
        #pragma unroll 1
        for (int k = 0; k < P/32; k++) {
            const int p0 = 4*sub + 32*k;
            float4 xv = *(const float4*)(xrow + p0);                 // conflict-free b128
            float4 nv = *(const float4*)(sm + LX_INVN + p0);         // 8-lane broadcast
            int4   lv = *(const int4*)((int*)sm + LX_LABS + p0);
            PROC(xv.x, nv.x, lv.x);
            PROC(xv.y, nv.y, lv.y);
            PROC(xv.z, nv.z, lv.z);
            PROC(xv.w, nv.w, lv.w);
        }
        __syncthreads();   // tile LDS reusable next iteration
    }

    // --- block reduction: fold 8 subs per d, then global f32 atomics ---
    // reuse sm: red[t][j], stride 39 -> 256*39 = 9984 floats = LTOT exactly
    #pragma unroll
    for (int c = 0; c < CC; c++) {
        sm[t*39 + c]      = aS[c];
        sm[t*39 + 19 + c] = aN[c];
    }
    __syncthreads();
    for (int i = t; i < 32*38; i += NT1) {
        const int dI = i / 38, j = i % 38;
        float s = 0.f;
        #pragma unroll
        for (int su = 0; su < 8; su++) s += sm[(dI*8 + su)*39 + j];
        const int gi = (j < 19) ? (j*CSTRIDE + dI) : ((j - 19)*CSTRIDE + 32 + dI);
        unsafeAtomicAdd(acc + gi, s);
    }
}

// Final: tiny 19-class epilogue. 1 block x 256 threads, deterministic reduction.
__global__ void k3_final(const float* __restrict__ gacc, float* __restrict__ out)
{
    __shared__ float acc[ACCSZ];
    __shared__ float cn[CC];
    __shared__ float pres[CC];
    __shared__ float red[256];
    const int t = threadIdx.x;

    for (int i = t; i < ACCSZ; i += 256) acc[i] = gacc[i];
    __syncthreads();

    float part = 0.f;

    // per-class: norms, presence, sim term
    // cosine is scale-invariant in the center, so raw sums replace centers:
    // seg_cos_c = (sums_c . S_c) / |sums_c|,  S_c = sum_{n in c} x_n/|x_n|
    if (t < CC) {
        const float* a = acc + t * CSTRIDE;
        float n2 = 0.f, dotS = 0.f;
        #pragma unroll
        for (int dd = 0; dd < DD; dd++) {
            n2   = fmaf(a[dd], a[dd], n2);
            dotS = fmaf(a[dd], a[32 + dd], dotS);
        }
        float count = a[64];
        float den   = fmaxf(count, 1.f);
        float norm  = sqrtf(n2);
        cn[t]   = norm;
        pres[t] = (count > 0.f) ? 1.f : 0.f;
        float segcos = (norm > 0.f) ? (dotS / norm) : 0.f;
        part += (count > 0.f) ? (1.f - segcos / den) : 0.f;
    }
    __syncthreads();

    // diff loss: 19x19 pair terms on raw sums (denominators cancel in cosine)
    for (int p = t; p < CC * CC; p += 256) {
        int i = p / CC, j = p % CC;
        const float* ai = acc + i * CSTRIDE;
        const float* aj = acc + j * CSTRIDE;
        float dot = 0.f;
        #pragma unroll
        for (int dd = 0; dd < DD; dd++) dot = fmaf(ai[dd], aj[dd], dot);
        float ddn  = fmaxf(cn[i] * cn[j], EPSF);
        float cs   = dot / ddn;
        float term = (i == j) ? (1.f - cs) : fmaxf(cs, 0.f);
        part += pres[i] * term * (1.f / (float)CC);
    }

    red[t] = part;
    __syncthreads();
    #pragma unroll
    for (int s = 128; s > 0; s >>= 1) {
        if (t < s) red[t] += red[t + s];
        __syncthreads();
    }
    if (t == 0) out[0] = red[0];
}

extern "C" void kernel_launch(void* const* d_in, const int* in_sizes, int n_in,
                              void* d_out, int out_size, void* d_ws, size_t ws_size,
                              hipStream_t stream)
{
    const float* in  = (const float*)d_in[0];
    const int*   tgt = (const int*)d_in[1];   // harness delivers integer inputs as int32
    float* out = (float*)d_out;
    float* acc = (float*)d_ws;                // 1235 floats ~ 5 KB

    hipLaunchKernelGGL(k0_zero,  dim3((ACCSZ + 255) / 256), dim3(256), 0, stream, acc);
    hipLaunchKernelGGL(k_count,  dim3(NCB),  dim3(256), 0, stream, tgt, acc);
    hipLaunchKernelGGL(k1_accum, dim3(NB1),  dim3(256), 0, stream, in, tgt, acc);
    hipLaunchKernelGGL(k3_final, dim3(1),    dim3(256), 0, stream, acc, out);
}